// Round 6
// baseline (228.569 us; speedup 1.0000x reference)
//
#include <hip/hip_runtime.h>

// out[n][p][m] = sum_c x[n][c][p] * rm[n][c][m]
// N=16, C=64, P=65536, M=128. Memory-bound: 256MB read + 512MB write -> floor ~122us.
// v6 = v4 (161.6us) + 2-deep register prefetch (r[2][8]): tile-k loads issued at
//      iter k-2, so the barrier-top ds_write's in-order vmcnt wait covers loads
//      with two tile-rounds of latency budget. Everything else identical to v4.
//      (v5's union-buffer + launch_bounds(256,6) regressed to 197.9us: grid gives
//       exactly 4 blocks/CU, so occupancy could never rise -- reverted.)

#define NB   16
#define CDIM 64
#define PDIM 65536
#define MDIM 128
#define PT   128
#define BLOCKS_PER_N 64
#define TILES_PER_BLOCK 8
#define XS   132   // lds_x row stride (bf16)

typedef __attribute__((ext_vector_type(8))) short bf16x8;
typedef __attribute__((ext_vector_type(4))) float f32x4;

__device__ __forceinline__ unsigned short f2bf(float f) {
  union { float f; unsigned int u; } v; v.f = f;
  unsigned int u = v.u;
  u += 0x7fffu + ((u >> 16) & 1u);  // RNE
  return (unsigned short)(u >> 16);
}

// rm tile swizzle (verified): [m][64c] bf16, 16B-slot XOR
__device__ __forceinline__ int swz(int row, int col) {
  int slot = (col >> 3) ^ (row & 7);
  return row * 64 + slot * 8 + (col & 7);
}

// x tile: [c][p], p XOR-swizzled by c-group -> conflict-free (2-way) gathers.
// XOR touches only p bits 4-5, so 4-elem (8B) write chunks stay contiguous.
__device__ __forceinline__ int xswz(int c, int p) {
  return c * XS + (p ^ (((c >> 3) & 3) << 4));
}

__global__ __launch_bounds__(256, 4) void nlsa_kernel(
    const float* __restrict__ x, const float* __restrict__ rm,
    float* __restrict__ out) {
  __shared__ unsigned short lds_rm[MDIM * CDIM];  // 16KB
  __shared__ unsigned short lds_x[CDIM * XS];     // 16.5KB

  const int t = threadIdx.x;
  const int b = blockIdx.x;
  const int n  = b >> 6;
  const int bt = b & 63;

  const float* xn   = x  + (size_t)n * CDIM * PDIM;
  const float* rmn  = rm + (size_t)n * CDIM * MDIM;
  float*       outn = out + (size_t)n * PDIM * MDIM;

  const int cst = t >> 5;          // 0..7
  const int pst = (t & 31) * 4;    // 0..124

  float4 r[2][8];
  // issue tile-0 loads first so they fly under rm staging
  {
    const float* src = xn + (size_t)(bt * PT + pst);
#pragma unroll
    for (int it = 0; it < 8; ++it)
      r[0][it] = *(const float4*)(src + (size_t)(cst + it * 8) * PDIM);
  }

  // ---- stage rm[n] -> lds_rm[m][c] bf16 (once per block)
  {
    const int m  = t & 127;
    const int cb = (t >> 7) * 4;
#pragma unroll
    for (int it = 0; it < 8; ++it) {
      const int c0 = cb + it * 8;
      ushort4 v;
      v.x = f2bf(rmn[(c0 + 0) * MDIM + m]);
      v.y = f2bf(rmn[(c0 + 1) * MDIM + m]);
      v.z = f2bf(rmn[(c0 + 2) * MDIM + m]);
      v.w = f2bf(rmn[(c0 + 3) * MDIM + m]);
      *(ushort4*)&lds_rm[swz(m, c0)] = v;
    }
  }
  __syncthreads();

  const int w  = t >> 6;    // wave: m range [32w, 32w+32)
  const int l  = t & 63;
  const int lo = l & 15;
  const int g  = l >> 4;

  // A fragments (rm) in registers for the whole kernel (lds_rm never reused)
  bf16x8 a[2][2];
#pragma unroll
  for (int mt = 0; mt < 2; ++mt)
#pragma unroll
    for (int ks = 0; ks < 2; ++ks)
      a[mt][ks] = *(const bf16x8*)&lds_rm[swz(w * 32 + mt * 16 + lo,
                                              ks * 32 + g * 8)];

  // issue tile-1 loads (after syncthreads so its drain doesn't cover them)
  {
    const float* src = xn + (size_t)((bt + BLOCKS_PER_N) * PT + pst);
#pragma unroll
    for (int it = 0; it < 8; ++it)
      r[1][it] = *(const float4*)(src + (size_t)(cst + it * 8) * PDIM);
  }

  for (int k = 0; k < TILES_PER_BLOCK; ++k) {
    // barrier1: all waves done reading lds_x for tile k-1 (reads consumed
    // pre-barrier) -- raw barrier, no vm/store drain.
    asm volatile("" ::: "memory");
    __builtin_amdgcn_s_barrier();
    asm volatile("" ::: "memory");

    // write tile k (loaded at iter k-2) into lds_x; the compiler's in-order
    // vmcnt wait covers only the 8 oldest outstanding ops = tile-k loads.
#pragma unroll
    for (int it = 0; it < 8; ++it) {
      ushort4 v;
      v.x = f2bf(r[k & 1][it].x); v.y = f2bf(r[k & 1][it].y);
      v.z = f2bf(r[k & 1][it].z); v.w = f2bf(r[k & 1][it].w);
      *(ushort4*)&lds_x[xswz(cst + it * 8, pst)] = v;
    }

    // issue loads of tile k+2 into the just-freed buffer (2-deep prefetch)
    if (k + 2 < TILES_PER_BLOCK) {
      const float* src =
          xn + (size_t)((bt + (k + 2) * BLOCKS_PER_N) * PT + pst);
#pragma unroll
      for (int it = 0; it < 8; ++it)
        r[k & 1][it] = *(const float4*)(src + (size_t)(cst + it * 8) * PDIM);
    }

    // barrier2: lds_x writes visible; lgkm-only wait (store queue NOT drained)
    asm volatile("s_waitcnt lgkmcnt(0)" ::: "memory");
    __builtin_amdgcn_s_barrier();
    asm volatile("" ::: "memory");

    const int p_base = (bt + k * BLOCKS_PER_N) * PT;
#pragma unroll
    for (int pt_ = 0; pt_ < 8; ++pt_) {
      const int pl  = pt_ * 16 + lo;
      const int pls = pl ^ (g << 4);   // matches xswz for c-groups g and g+4
      bf16x8 b0, b1;
#pragma unroll
      for (int i = 0; i < 8; ++i) {
        b0[i] = (short)lds_x[(g * 8 + i) * XS + pls];
        b1[i] = (short)lds_x[(32 + g * 8 + i) * XS + pls];
      }
      f32x4 acc0 = {0.f, 0.f, 0.f, 0.f};
      f32x4 acc1 = {0.f, 0.f, 0.f, 0.f};
      acc0 = __builtin_amdgcn_mfma_f32_16x16x32_bf16(a[0][0], b0, acc0, 0, 0, 0);
      acc0 = __builtin_amdgcn_mfma_f32_16x16x32_bf16(a[0][1], b1, acc0, 0, 0, 0);
      acc1 = __builtin_amdgcn_mfma_f32_16x16x32_bf16(a[1][0], b0, acc1, 0, 0, 0);
      acc1 = __builtin_amdgcn_mfma_f32_16x16x32_bf16(a[1][1], b1, acc1, 0, 0, 0);

      float* dst = outn + (size_t)(p_base + pl) * MDIM + w * 32 + g * 4;
      *(f32x4*)(dst)      = acc0;   // m = 32w + 4g + {0..3}
      *(f32x4*)(dst + 16) = acc1;   // m = 32w + 16 + 4g + {0..3}
    }
  }
}

extern "C" void kernel_launch(void* const* d_in, const int* in_sizes, int n_in,
                              void* d_out, int out_size, void* d_ws, size_t ws_size,
                              hipStream_t stream) {
  const float* x  = (const float*)d_in[0];   // (N, C, H, W) fp32
  const float* rm = (const float*)d_in[1];   // (N, C, M) fp32
  float* out = (float*)d_out;                // (N, P, M) fp32
  nlsa_kernel<<<dim3(NB * BLOCKS_PER_N), dim3(256), 0, stream>>>(x, rm, out);
}

// Round 7
// 177.673 us; speedup vs baseline: 1.2865x; 1.2865x over previous
//
#include <hip/hip_runtime.h>

// out[n][p][m] = sum_c x[n][c][p] * rm[n][c][m]
// N=16, C=64, P=65536, M=128. Memory-bound: 256MB read + 512MB write -> floor ~122us.
// v7 = v4 (161.6us) + concurrency 16->20 waves/CU:
//   - XS 132->128: LDS = 16KB(rm) + 16KB(x) = 32KB exact -> 5 blocks/CU capacity
//     (banks re-verified: writes 2-way free; gather swizzle tiles all 32 banks)
//   - grid 1024->1280 (5 blocks/CU exact): n = bid&15, window w = (bid>>4) + 80j
//   - __launch_bounds__(256,5): VGPR cap 102
// Rationale: v6 (+32 VGPR) lost exactly 4/3 perf = one block/CU -> latency-bound,
// scales with resident waves. v5 failed b/c grid=1024 caps blocks/CU at 4.

#define NB   16
#define CDIM 64
#define PDIM 65536
#define MDIM 128
#define PT   128
#define NWIN 512          // PDIM / PT
#define WSTRIDE 80        // 1280 blocks / 16 n
#define XS   128          // lds_x row stride (bf16) -> exactly 16KB

typedef __attribute__((ext_vector_type(8))) short bf16x8;
typedef __attribute__((ext_vector_type(4))) float f32x4;

__device__ __forceinline__ unsigned short f2bf(float f) {
  union { float f; unsigned int u; } v; v.f = f;
  unsigned int u = v.u;
  u += 0x7fffu + ((u >> 16) & 1u);  // RNE
  return (unsigned short)(u >> 16);
}

// rm tile swizzle (verified): [m][64c] bf16, 16B-slot XOR
__device__ __forceinline__ int swz(int row, int col) {
  int slot = (col >> 3) ^ (row & 7);
  return row * 64 + slot * 8 + (col & 7);
}

// x tile: [c][p], p XOR-swizzled by c-group. At XS=128: write banks 2-way free
// (lanes l, l+16 alias); gather banks ((pt_^g)&3)*8 + lo/2 -> 32-bank tiling,
// 2-way free. XOR touches only p bits 4-5, so 8B write chunks stay contiguous.
__device__ __forceinline__ int xswz(int c, int p) {
  return c * XS + (p ^ (((c >> 3) & 3) << 4));
}

__global__ __launch_bounds__(256, 5) void nlsa_kernel(
    const float* __restrict__ x, const float* __restrict__ rm,
    float* __restrict__ out) {
  __shared__ unsigned short lds_rm[MDIM * CDIM];  // 16KB
  __shared__ unsigned short lds_x[CDIM * XS];     // 16KB  (total exactly 32KB)

  const int t = threadIdx.x;
  const int b = blockIdx.x;
  const int n  = b & 15;           // constant n per block -> rm staged once
  const int w0 = b >> 4;           // first p-window, stride WSTRIDE

  const float* xn   = x  + (size_t)n * CDIM * PDIM;
  const float* rmn  = rm + (size_t)n * CDIM * MDIM;
  float*       outn = out + (size_t)n * PDIM * MDIM;

  const int cst = t >> 5;          // 0..7
  const int pst = (t & 31) * 4;    // 0..124

  float4 r[8];
  // issue first-tile loads so they fly under rm staging
  {
    const float* src = xn + (size_t)(w0 * PT + pst);
#pragma unroll
    for (int it = 0; it < 8; ++it)
      r[it] = *(const float4*)(src + (size_t)(cst + it * 8) * PDIM);
  }

  // ---- stage rm[n] -> lds_rm[m][c] bf16 (once per block)
  {
    const int m  = t & 127;
    const int cb = (t >> 7) * 4;
#pragma unroll
    for (int it = 0; it < 8; ++it) {
      const int c0 = cb + it * 8;
      ushort4 v;
      v.x = f2bf(rmn[(c0 + 0) * MDIM + m]);
      v.y = f2bf(rmn[(c0 + 1) * MDIM + m]);
      v.z = f2bf(rmn[(c0 + 2) * MDIM + m]);
      v.w = f2bf(rmn[(c0 + 3) * MDIM + m]);
      *(ushort4*)&lds_rm[swz(m, c0)] = v;
    }
  }
  __syncthreads();

  const int w_  = t >> 6;   // wave: m range [32w_, 32w_+32)
  const int l   = t & 63;
  const int lo  = l & 15;
  const int g   = l >> 4;

  // A fragments (rm) in registers for the whole kernel (lds_rm never reused)
  bf16x8 a[2][2];
#pragma unroll
  for (int mt = 0; mt < 2; ++mt)
#pragma unroll
    for (int ks = 0; ks < 2; ++ks)
      a[mt][ks] = *(const bf16x8*)&lds_rm[swz(w_ * 32 + mt * 16 + lo,
                                              ks * 32 + g * 8)];

  for (int w = w0; w < NWIN; w += WSTRIDE) {
    // barrier1: all waves done reading lds_x for previous tile (reads consumed
    // pre-barrier) -- raw barrier, no vm/store drain.
    asm volatile("" ::: "memory");
    __builtin_amdgcn_s_barrier();
    asm volatile("" ::: "memory");

    // write staged tile into lds_x (compiler inserts counted vmcnt for r)
#pragma unroll
    for (int it = 0; it < 8; ++it) {
      ushort4 v;
      v.x = f2bf(r[it].x); v.y = f2bf(r[it].y);
      v.z = f2bf(r[it].z); v.w = f2bf(r[it].w);
      *(ushort4*)&lds_x[xswz(cst + it * 8, pst)] = v;
    }

    // prefetch next tile into r (overlaps the compute phase below)
    if (w + WSTRIDE < NWIN) {
      const float* src = xn + (size_t)((w + WSTRIDE) * PT + pst);
#pragma unroll
      for (int it = 0; it < 8; ++it)
        r[it] = *(const float4*)(src + (size_t)(cst + it * 8) * PDIM);
    }

    // barrier2: lds_x writes visible; lgkm-only wait (store queue NOT drained)
    asm volatile("s_waitcnt lgkmcnt(0)" ::: "memory");
    __builtin_amdgcn_s_barrier();
    asm volatile("" ::: "memory");

    const int p_base = w * PT;
#pragma unroll
    for (int pt_ = 0; pt_ < 8; ++pt_) {
      const int pl  = pt_ * 16 + lo;
      const int pls = pl ^ (g << 4);   // matches xswz for c-groups g and g+4
      bf16x8 b0, b1;
#pragma unroll
      for (int i = 0; i < 8; ++i) {
        b0[i] = (short)lds_x[(g * 8 + i) * XS + pls];
        b1[i] = (short)lds_x[(32 + g * 8 + i) * XS + pls];
      }
      f32x4 acc0 = {0.f, 0.f, 0.f, 0.f};
      f32x4 acc1 = {0.f, 0.f, 0.f, 0.f};
      acc0 = __builtin_amdgcn_mfma_f32_16x16x32_bf16(a[0][0], b0, acc0, 0, 0, 0);
      acc0 = __builtin_amdgcn_mfma_f32_16x16x32_bf16(a[0][1], b1, acc0, 0, 0, 0);
      acc1 = __builtin_amdgcn_mfma_f32_16x16x32_bf16(a[1][0], b0, acc1, 0, 0, 0);
      acc1 = __builtin_amdgcn_mfma_f32_16x16x32_bf16(a[1][1], b1, acc1, 0, 0, 0);

      float* dst = outn + (size_t)(p_base + pl) * MDIM + w_ * 32 + g * 4;
      *(f32x4*)(dst)      = acc0;   // m = 32w_ + 4g + {0..3}
      *(f32x4*)(dst + 16) = acc1;   // m = 32w_ + 16 + 4g + {0..3}
    }
  }
}

extern "C" void kernel_launch(void* const* d_in, const int* in_sizes, int n_in,
                              void* d_out, int out_size, void* d_ws, size_t ws_size,
                              hipStream_t stream) {
  const float* x  = (const float*)d_in[0];   // (N, C, H, W) fp32
  const float* rm = (const float*)d_in[1];   // (N, C, M) fp32
  float* out = (float*)d_out;                // (N, P, M) fp32
  nlsa_kernel<<<dim3(NB * WSTRIDE), dim3(256), 0, stream>>>(x, rm, out);
}